// Round 2
// baseline (238.239 us; speedup 1.0000x reference)
//
#include <hip/hip_runtime.h>
#include <cstdint>
#include <cstddef>

#define N_COLS 4096
#define TPB 256
#define NCOPY 16
#define HSTRIDE 257   // spread the 16 copies of a hot bin across banks
#define CAND_CAP 256

// --- kernel 1: boost factors, double-precision exp rounded to fp32 ---
__global__ void boost_kernel(const float* __restrict__ dc,
                             const int* __restrict__ kp,
                             float* __restrict__ bf) {
    int i = blockIdx.x * blockDim.x + threadIdx.x;
    if (i < N_COLS) {
        float td = (float)kp[0] / (float)N_COLS;   // float32(k)/float32(n), like ref
        float arg = td - dc[i];                    // fp32 subtract, like ref
        bf[i] = (float)exp((double)arg);           // ~correctly-rounded fp32 exp
    }
}

__device__ __forceinline__ uint32_t orderable(float f) {
    uint32_t u = __float_as_uint(f);
    // monotone bijection: float order == unsigned order
    return (u & 0x80000000u) ? ~u : (u | 0x80000000u);
}

// one block per row; 16 boosted bit patterns per thread held in registers
__global__ __launch_bounds__(TPB) void kwinner_kernel(
    const float* __restrict__ x, const float* __restrict__ bf,
    const int* __restrict__ kp, float* __restrict__ out)
{
    __shared__ uint32_t s_hist[NCOPY * HSTRIDE];
    __shared__ uint32_t s_cnt[256];
    __shared__ uint32_t s_cand[CAND_CAP];
    __shared__ uint32_t s_m2;
    __shared__ uint32_t s_sel;

    const int tid = threadIdx.x;
    const int lane = tid & 63;
    const size_t row = blockIdx.x;
    const float4* xr = (const float4*)(x + row * (size_t)N_COLS);
    const float4* br = (const float4*)bf;
    float4* orow = (float4*)(out + row * (size_t)N_COLS);

    uint32_t u[16];
    #pragma unroll
    for (int j = 0; j < 4; ++j) {
        float4 v = xr[tid + j * TPB];
        float4 b = br[tid + j * TPB];
        u[j * 4 + 0] = orderable(v.x * b.x);
        u[j * 4 + 1] = orderable(v.y * b.y);
        u[j * 4 + 2] = orderable(v.z * b.z);
        u[j * 4 + 3] = orderable(v.w * b.w);
    }

    // one-time LDS init (clears are fused into reduce phases afterwards)
    for (int i = tid; i < NCOPY * HSTRIDE; i += TPB) s_hist[i] = 0;
    if (tid == 0) s_m2 = 0;
    __syncthreads();

    uint32_t rem = (uint32_t)kp[0];   // 1-indexed rank of element we seek
    uint32_t prefix = 0;
    const uint32_t base = (uint32_t)(tid & (NCOPY - 1)) * HSTRIDE;

    // one 8-bit radix pass: histogram -> reduce(+clear) -> replicated scan.
    // 2 barriers. Updates prefix/rem uniformly across the block.
    auto hist_pass = [&](int shift, uint32_t pm) {
        #pragma unroll
        for (int e = 0; e < 16; ++e) {
            uint32_t uu = u[e];
            if (((uu ^ prefix) & pm) == 0u)
                atomicAdd(&s_hist[base + ((uu >> shift) & 255u)], 1u);
        }
        __syncthreads();
        // thread t owns bin t: sum the 16 copies and zero them for next pass
        uint32_t c = 0;
        #pragma unroll
        for (int cc = 0; cc < NCOPY; ++cc) {
            int idx = cc * HSTRIDE + tid;
            c += s_hist[idx];
            s_hist[idx] = 0;
        }
        s_cnt[tid] = c;
        __syncthreads();
        // every wave redundantly computes the same suffix-scan + digit pick
        uint4 v = ((const uint4*)s_cnt)[lane];
        uint32_t s3 = v.w;
        uint32_t s2 = v.z + s3;
        uint32_t s1 = v.y + s2;
        uint32_t s0 = v.x + s1;
        uint32_t T = s0;
        #pragma unroll
        for (int off = 1; off < 64; off <<= 1) {
            uint32_t t = (uint32_t)__shfl_down((int)T, off, 64);
            if (lane + off < 64) T += t;
        }
        uint32_t Tex = T - s0;                // sum over lanes > lane
        uint32_t S0 = Tex + s0, S1 = Tex + s1, S2 = Tex + s2, S3 = Tex + s3;
        int b = -1; uint32_t sn = 0;
        if (S3 >= rem)      { b = 3; sn = S3 - v.w; }
        else if (S2 >= rem) { b = 2; sn = S2 - v.z; }
        else if (S1 >= rem) { b = 1; sn = S1 - v.y; }
        else if (S0 >= rem) { b = 0; sn = S0 - v.x; }
        uint32_t packed = (b >= 0)
            ? (((uint32_t)(4 * lane + b + 1) << 16) | sn)   // sn < 4096 fits 16b
            : 0u;
        #pragma unroll
        for (int off = 1; off < 64; off <<= 1) {
            uint32_t o = (uint32_t)__shfl_xor((int)packed, off, 64);
            packed = packed > o ? packed : o;
        }
        uint32_t d = (packed >> 16) - 1u;
        sn = packed & 0xFFFFu;
        rem -= sn;
        prefix |= d << shift;
    };

    hist_pass(24, 0u);
    hist_pass(16, 0xFF000000u);

    // compact candidates matching the 16-bit prefix (typically ~7 of them)
    #pragma unroll
    for (int e = 0; e < 16; ++e) {
        uint32_t uu = u[e];
        if (((uu ^ prefix) & 0xFFFF0000u) == 0u) {
            uint32_t pos = atomicAdd(&s_m2, 1u);
            if (pos < CAND_CAP) s_cand[pos] = uu;
        }
    }
    __syncthreads();

    const uint32_t m2 = s_m2;     // block-uniform
    uint32_t thr;
    if (m2 <= CAND_CAP) {
        // wave 0: exact bitwise descent over the low 16 bits via ballots
        if (tid < 64) {
            uint32_t inval = ~prefix;   // differs in high bits -> never matches
            uint32_t e0 = (lane       < m2) ? s_cand[lane      ] : inval;
            uint32_t e1 = (lane + 64  < m2) ? s_cand[lane + 64 ] : inval;
            uint32_t e2 = (lane + 128 < m2) ? s_cand[lane + 128] : inval;
            uint32_t e3 = (lane + 192 < m2) ? s_cand[lane + 192] : inval;
            uint32_t cur = 0;
            #pragma unroll
            for (int bpos = 15; bpos >= 0; --bpos) {
                uint32_t t = prefix | cur | (1u << bpos);
                uint32_t mask = ~((1u << bpos) - 1u);
                uint32_t c = (uint32_t)__popcll(__ballot(((e0 ^ t) & mask) == 0u))
                           + (uint32_t)__popcll(__ballot(((e1 ^ t) & mask) == 0u))
                           + (uint32_t)__popcll(__ballot(((e2 ^ t) & mask) == 0u))
                           + (uint32_t)__popcll(__ballot(((e3 ^ t) & mask) == 0u));
                if (c >= rem) cur |= (1u << bpos);
                else          rem -= c;
            }
            if (tid == 0) s_sel = prefix | cur;
        }
        __syncthreads();
        thr = s_sel;
    } else {
        // adversarial-data fallback: finish with generic radix passes
        hist_pass(8, 0xFFFF0000u);
        hist_pass(0, 0xFFFFFF00u);
        thr = prefix;
    }

    // epilogue: reload x (L2/L3-hot), apply exact mask
    #pragma unroll
    for (int j = 0; j < 4; ++j) {
        float4 v = xr[tid + j * TPB];
        float4 o;
        o.x = (u[j * 4 + 0] >= thr) ? v.x : 0.0f;
        o.y = (u[j * 4 + 1] >= thr) ? v.y : 0.0f;
        o.z = (u[j * 4 + 2] >= thr) ? v.z : 0.0f;
        o.w = (u[j * 4 + 3] >= thr) ? v.w : 0.0f;
        orow[tid + j * TPB] = o;
    }
}

extern "C" void kernel_launch(void* const* d_in, const int* in_sizes, int n_in,
                              void* d_out, int out_size, void* d_ws, size_t ws_size,
                              hipStream_t stream) {
    const float* x  = (const float*)d_in[0];
    const float* dc = (const float*)d_in[1];
    const int*   kp = (const int*)d_in[2];
    float* out = (float*)d_out;
    float* bf  = (float*)d_ws;                 // 4096 floats of scratch

    const int n    = in_sizes[1];              // 4096
    const int rows = in_sizes[0] / n;          // 8192

    boost_kernel<<<(n + TPB - 1) / TPB, TPB, 0, stream>>>(dc, kp, bf);
    kwinner_kernel<<<rows, TPB, 0, stream>>>(x, bf, kp, out);
}